// Round 8
// baseline (127.643 us; speedup 1.0000x reference)
//
#include <hip/hip_runtime.h>

// CapsuleLayer dynamic routing — round 8: residency fix.
// x: [B=256, R=1152, I=8] f32; W: [C=10, R=1152, I=8, O=16] f32
// out: v = [B, C, 1, 1, O=16] f32
//
// Rounds 5-7 all pinned at ~70us: per-thread state (~88 VGPR at T=512) left
// only ~7 waves/CU resident -> W L2 stream latency exposed (L2 floor ~25us,
// VALU ~16us). This round keeps BPB=2 W-traffic but shrinks state:
//  - T=1024, 8-lane groups per route node (lane owns an OUTPUT PAIR):
//    u = 9 passes x 2 outs x 2 batches = 36 fp32/thread.
//  - No logit registers: b_t = u . (sum_{tau<t} v_tau), so keep running
//    vsum[16] per batch in LDS and recompute e = exp(u . vsum) per iteration
//    (same FLOPs - the agreement dot was computed anyway; exp(0)=1 at it0).
//  -> ~55 live VGPR, LB(1024,2) caps at 64 -> 2 blocks/CU = 32 waves possible.
//  - XCD-chunked swizzle (1280 = 8*160, bijective): each XCD's L2 holds ~1-2
//    W[c] slices (590KB-1.2MB) instead of all 10 (5.9MB > 4MB -> thrash).
// W loads: 8 lanes x float2 cover a full 64B line -> coalesced.

#define B_ 256
#define C_ 10
#define R_ 1152
#define I_ 8
#define O_ 16
#define T_ 1024
#define BPB 2            // batches per block
#define GRP 8            // lanes per route node
#define RPP 128          // r's per pass = T_/GRP
#define KPT 9            // passes = R_/RPP
#define NW 16            // waves per block
#define NITER 3
#define NXCD 8

__global__ __launch_bounds__(T_, 2) void capsule_routing_kernel(
    const float* __restrict__ x,   // [B, R, I]
    const float* __restrict__ w,   // [C, R, I, O]
    float* __restrict__ out)       // [B, C, O]
{
    // XCD-chunked bijective swizzle: grid 1280 = 8 * 160
    const int wg = (blockIdx.x & (NXCD - 1)) * (C_ * (B_ / BPB) / NXCD)
                 + (blockIdx.x >> 3);
    const int c    = wg >> 7;          // 128 b-pairs per c, c-major
    const int bh   = wg & 127;
    const int b0   = bh * BPB;
    const int tid  = threadIdx.x;
    const int lane = tid & 63;
    const int wid  = tid >> 6;
    const int g    = tid & 7;          // owns outputs {2g, 2g+1}
    const int rl   = tid >> 3;         // route-node slot within pass [0,128)

    __shared__ float sred[BPB][NW][GRP][2];  // per-wave partial s by o-pair
    __shared__ float zred[BPB][NW];          // per-wave partial Z
    __shared__ float vsum[BPB][O_];          // running sum of v over iterations

    float u0[KPT][2], u1[KPT][2];   // 36 fp32 total

    if (tid < BPB * O_) vsum[tid >> 4][tid & 15] = 0.f;

    // ---- u[bb][r, 2g..2g+1] = x[b0+bb,r,:] @ W[c,r,:,2g..2g+1] ----
    #pragma unroll
    for (int k = 0; k < KPT; ++k) {
        const int r = k * RPP + rl;
        const float4* xp0 = (const float4*)(x + ((size_t)b0 * R_ + r) * I_);
        const float4 xa0 = xp0[0];
        const float4 xb0 = xp0[1];
        const float4* xp1 = (const float4*)(x + ((size_t)(b0 + 1) * R_ + r) * I_);
        const float4 xa1 = xp1[0];
        const float4 xb1 = xp1[1];
        const float xs0[8] = {xa0.x, xa0.y, xa0.z, xa0.w, xb0.x, xb0.y, xb0.z, xb0.w};
        const float xs1[8] = {xa1.x, xa1.y, xa1.z, xa1.w, xb1.x, xb1.y, xb1.z, xb1.w};
        const float* wp = w + ((size_t)c * R_ + r) * (I_ * O_) + g * 2;
        float a00 = 0.f, a01 = 0.f, a10 = 0.f, a11 = 0.f;
        #pragma unroll
        for (int i = 0; i < I_; ++i) {
            const float2 wv = *(const float2*)(wp + i * O_);  // group covers 64B line
            a00 += xs0[i] * wv.x;  a01 += xs0[i] * wv.y;
            a10 += xs1[i] * wv.x;  a11 += xs1[i] * wv.y;
        }
        u0[k][0] = a00; u0[k][1] = a01;
        u1[k][0] = a10; u1[k][1] = a11;
    }
    __syncthreads();   // vsum init visible

    // ---- routing iterations (logits recomputed from vsum) ----
    for (int it = 0; it < NITER; ++it) {
        const float2 vs0 = *(const float2*)&vsum[0][g * 2];
        const float2 vs1 = *(const float2*)&vsum[1][g * 2];
        float z0 = 0.f, z1 = 0.f;
        float s00 = 0.f, s01 = 0.f, s10 = 0.f, s11 = 0.f;
        #pragma unroll
        for (int k = 0; k < KPT; ++k) {
            // logit = u . vsum, reduced over the 8-lane group
            float d0 = u0[k][0] * vs0.x + u0[k][1] * vs0.y;
            float d1 = u1[k][0] * vs1.x + u1[k][1] * vs1.y;
            d0 += __shfl_xor(d0, 1); d1 += __shfl_xor(d1, 1);
            d0 += __shfl_xor(d0, 2); d1 += __shfl_xor(d1, 2);
            d0 += __shfl_xor(d0, 4); d1 += __shfl_xor(d1, 4);
            const float e0 = __expf(d0);
            const float e1 = __expf(d1);
            z0 += e0;  s00 += e0 * u0[k][0];  s01 += e0 * u0[k][1];
            z1 += e1;  s10 += e1 * u1[k][0];  s11 += e1 * u1[k][1];
        }
        // butterfly across the 8 groups within the wave (g kept fixed)
        #pragma unroll
        for (int off = 8; off <= 32; off <<= 1) {
            z0 += __shfl_xor(z0, off);   z1 += __shfl_xor(z1, off);
            s00 += __shfl_xor(s00, off); s01 += __shfl_xor(s01, off);
            s10 += __shfl_xor(s10, off); s11 += __shfl_xor(s11, off);
        }
        if (lane < GRP) {   // lane == g here
            sred[0][wid][lane][0] = s00; sred[0][wid][lane][1] = s01;
            sred[1][wid][lane][0] = s10; sred[1][wid][lane][1] = s11;
            if (lane == 0) { zred[0][wid] = z0; zred[1][wid] = z1; }
        }
        __syncthreads();

        // wave 0 finalizes both b's: lanes 0-15 -> b0, 16-31 -> b0+1
        if (wid == 0 && lane < 2 * O_) {
            const int bb = lane >> 4;
            const int o  = lane & 15;
            float S = 0.f, Z = 0.f;
            #pragma unroll
            for (int wv = 0; wv < NW; ++wv) {
                S += sred[bb][wv][o >> 1][o & 1];
                Z += zred[bb][wv];
            }
            const float inv = 1.f / Z;
            const float svn = S * inv;
            float p = svn * svn;   // butterfly within 16-lane group -> |s|^2
            p += __shfl_xor(p, 1);
            p += __shfl_xor(p, 2);
            p += __shfl_xor(p, 4);
            p += __shfl_xor(p, 8);
            const float scale = sqrtf(p) / (1.f + p);
            const float vf = svn * scale;
            vsum[bb][o] += vf;
            if (it == NITER - 1)
                out[((size_t)(b0 + bb) * C_ + c) * O_ + o] = vf;
        }
        if (it != NITER - 1) __syncthreads();   // vsum update visible
    }
}

extern "C" void kernel_launch(void* const* d_in, const int* in_sizes, int n_in,
                              void* d_out, int out_size, void* d_ws, size_t ws_size,
                              hipStream_t stream) {
    const float* x = (const float*)d_in[0];
    const float* w = (const float*)d_in[1];
    float* out = (float*)d_out;
    capsule_routing_kernel<<<dim3(C_ * (B_ / BPB)), dim3(T_), 0, stream>>>(x, w, out);
}

// Round 9
// 127.114 us; speedup vs baseline: 1.0042x; 1.0042x over previous
//
#include <hip/hip_runtime.h>

// CapsuleLayer dynamic routing — round 9: round-8 structure, swizzle REMOVED.
// x: [B=256, R=1152, I=8] f32; W: [C=10, R=1152, I=8, O=16] f32
// out: v = [B, C, 1, 1, O=16] f32
//
// Round-8 post-mortem: dur tracks FETCH/~400GB/s across ALL rounds; the XCD
// swizzle doubled FETCH (broke the natural mapping's cross-c x reuse: without
// swizzle each XCD always gets the same b-residues for every c, so its x
// slice stays L2-resident, while all XCDs share the same hot W[c] in time).
// This round: natural c-major block order (wg = blockIdx.x), keeping round-8's
// low-state structure:
//  - T=1024, 8-lane groups per route node (lane owns an OUTPUT PAIR):
//    u = 9 passes x 2 outs x 2 batches = 36 fp32/thread -> 52 VGPR.
//  - No logit registers: recompute e = exp(u . vsum) from running vsum in LDS
//    (exp(0)=1 at it0 gives uniform c free; same FLOPs as explicit agreement).
//  - LB(1024,2): 2 blocks/CU co-resident (tiny LDS), ~14-16 waves/CU.
// A/B vs round 8 isolates the swizzle; vs round 7 isolates residency.

#define B_ 256
#define C_ 10
#define R_ 1152
#define I_ 8
#define O_ 16
#define T_ 1024
#define BPB 2            // batches per block
#define GRP 8            // lanes per route node
#define RPP 128          // r's per pass = T_/GRP
#define KPT 9            // passes = R_/RPP
#define NW 16            // waves per block
#define NITER 3

__global__ __launch_bounds__(T_, 2) void capsule_routing_kernel(
    const float* __restrict__ x,   // [B, R, I]
    const float* __restrict__ w,   // [C, R, I, O]
    float* __restrict__ out)       // [B, C, O]
{
    const int wg   = blockIdx.x;       // natural order (no swizzle)
    const int c    = wg >> 7;          // 128 b-pairs per c, c-major
    const int bh   = wg & 127;
    const int b0   = bh * BPB;
    const int tid  = threadIdx.x;
    const int lane = tid & 63;
    const int wid  = tid >> 6;
    const int g    = tid & 7;          // owns outputs {2g, 2g+1}
    const int rl   = tid >> 3;         // route-node slot within pass [0,128)

    __shared__ float sred[BPB][NW][GRP][2];  // per-wave partial s by o-pair
    __shared__ float zred[BPB][NW];          // per-wave partial Z
    __shared__ float vsum[BPB][O_];          // running sum of v over iterations

    float u0[KPT][2], u1[KPT][2];   // 36 fp32 total

    if (tid < BPB * O_) vsum[tid >> 4][tid & 15] = 0.f;

    // ---- u[bb][r, 2g..2g+1] = x[b0+bb,r,:] @ W[c,r,:,2g..2g+1] ----
    #pragma unroll
    for (int k = 0; k < KPT; ++k) {
        const int r = k * RPP + rl;
        const float4* xp0 = (const float4*)(x + ((size_t)b0 * R_ + r) * I_);
        const float4 xa0 = xp0[0];
        const float4 xb0 = xp0[1];
        const float4* xp1 = (const float4*)(x + ((size_t)(b0 + 1) * R_ + r) * I_);
        const float4 xa1 = xp1[0];
        const float4 xb1 = xp1[1];
        const float xs0[8] = {xa0.x, xa0.y, xa0.z, xa0.w, xb0.x, xb0.y, xb0.z, xb0.w};
        const float xs1[8] = {xa1.x, xa1.y, xa1.z, xa1.w, xb1.x, xb1.y, xb1.z, xb1.w};
        const float* wp = w + ((size_t)c * R_ + r) * (I_ * O_) + g * 2;
        float a00 = 0.f, a01 = 0.f, a10 = 0.f, a11 = 0.f;
        #pragma unroll
        for (int i = 0; i < I_; ++i) {
            const float2 wv = *(const float2*)(wp + i * O_);  // group covers 64B line
            a00 += xs0[i] * wv.x;  a01 += xs0[i] * wv.y;
            a10 += xs1[i] * wv.x;  a11 += xs1[i] * wv.y;
        }
        u0[k][0] = a00; u0[k][1] = a01;
        u1[k][0] = a10; u1[k][1] = a11;
    }
    __syncthreads();   // vsum init visible

    // ---- routing iterations (logits recomputed from vsum) ----
    for (int it = 0; it < NITER; ++it) {
        const float2 vs0 = *(const float2*)&vsum[0][g * 2];
        const float2 vs1 = *(const float2*)&vsum[1][g * 2];
        float z0 = 0.f, z1 = 0.f;
        float s00 = 0.f, s01 = 0.f, s10 = 0.f, s11 = 0.f;
        #pragma unroll
        for (int k = 0; k < KPT; ++k) {
            // logit = u . vsum, reduced over the 8-lane group
            float d0 = u0[k][0] * vs0.x + u0[k][1] * vs0.y;
            float d1 = u1[k][0] * vs1.x + u1[k][1] * vs1.y;
            d0 += __shfl_xor(d0, 1); d1 += __shfl_xor(d1, 1);
            d0 += __shfl_xor(d0, 2); d1 += __shfl_xor(d1, 2);
            d0 += __shfl_xor(d0, 4); d1 += __shfl_xor(d1, 4);
            const float e0 = __expf(d0);
            const float e1 = __expf(d1);
            z0 += e0;  s00 += e0 * u0[k][0];  s01 += e0 * u0[k][1];
            z1 += e1;  s10 += e1 * u1[k][0];  s11 += e1 * u1[k][1];
        }
        // butterfly across the 8 groups within the wave (g kept fixed)
        #pragma unroll
        for (int off = 8; off <= 32; off <<= 1) {
            z0 += __shfl_xor(z0, off);   z1 += __shfl_xor(z1, off);
            s00 += __shfl_xor(s00, off); s01 += __shfl_xor(s01, off);
            s10 += __shfl_xor(s10, off); s11 += __shfl_xor(s11, off);
        }
        if (lane < GRP) {   // lane == g here
            sred[0][wid][lane][0] = s00; sred[0][wid][lane][1] = s01;
            sred[1][wid][lane][0] = s10; sred[1][wid][lane][1] = s11;
            if (lane == 0) { zred[0][wid] = z0; zred[1][wid] = z1; }
        }
        __syncthreads();

        // wave 0 finalizes both b's: lanes 0-15 -> b0, 16-31 -> b0+1
        if (wid == 0 && lane < 2 * O_) {
            const int bb = lane >> 4;
            const int o  = lane & 15;
            float S = 0.f, Z = 0.f;
            #pragma unroll
            for (int wv = 0; wv < NW; ++wv) {
                S += sred[bb][wv][o >> 1][o & 1];
                Z += zred[bb][wv];
            }
            const float inv = 1.f / Z;
            const float svn = S * inv;
            float p = svn * svn;   // butterfly within 16-lane group -> |s|^2
            p += __shfl_xor(p, 1);
            p += __shfl_xor(p, 2);
            p += __shfl_xor(p, 4);
            p += __shfl_xor(p, 8);
            const float scale = sqrtf(p) / (1.f + p);
            const float vf = svn * scale;
            vsum[bb][o] += vf;
            if (it == NITER - 1)
                out[((size_t)(b0 + bb) * C_ + c) * O_ + o] = vf;
        }
        if (it != NITER - 1) __syncthreads();   // vsum update visible
    }
}

extern "C" void kernel_launch(void* const* d_in, const int* in_sizes, int n_in,
                              void* d_out, int out_size, void* d_ws, size_t ws_size,
                              hipStream_t stream) {
    const float* x = (const float*)d_in[0];
    const float* w = (const float*)d_in[1];
    float* out = (float*)d_out;
    capsule_routing_kernel<<<dim3(C_ * (B_ / BPB)), dim3(T_), 0, stream>>>(x, w, out);
}

// Round 10
// 70.574 us; speedup vs baseline: 1.8087x; 1.8012x over previous
//
#include <hip/hip_runtime.h>

// CapsuleLayer dynamic routing — round 10: BPB=4 via bf16-packed u registers.
// x: [B=256, R=1152, I=8] f32; W: [C=10, R=1152, I=8, O=16] f32
// out: v = [B, C, 1, 1, O=16] f32
//
// Round-9 finding: memory phase is bound by VMEM issue slots, not bytes
// (GRP=8's float2 W loads doubled instr count at same FETCH -> 2x dur).
// So: keep GRP=4 (lane reads 16B dwordx4, quad covers a 64B W line) and halve
// the W slot count the only way left: 4 batches per block (grid 640,
// W stream 377MB, 2x fewer W instrs than r7 per byte of W).
// Register fit: u stored as bf16 pairs (4b x 9k x 2 regs = 72 VGPR); NO logit
// registers - logits recomputed as u . vsum (vsum[4][16] in LDS, running sum
// of v; identical FLOPs to the agreement update it replaces; exp(0)=1 at it0).
// Peak ~125 VGPR < 128 cap from LB(512,2). Precision: bf16 u -> ~5e-3 absmax
// (threshold 1.7e-2).

#define B_ 256
#define C_ 10
#define R_ 1152
#define I_ 8
#define O_ 16
#define T_ 512
#define BPB 4            // batches per block
#define RPP 128          // r's per pass = T_/4
#define KPT 9            // passes = R_/RPP
#define NW 8             // waves per block
#define NITER 3

__device__ __forceinline__ uint32_t bf16_rn(float f) {
    uint32_t u = __builtin_bit_cast(uint32_t, f);
    return (u + 0x7FFFu + ((u >> 16) & 1u)) >> 16;
}
__device__ __forceinline__ uint32_t pack2(float lo, float hi) {
    return bf16_rn(lo) | (bf16_rn(hi) << 16);
}
__device__ __forceinline__ float unlo(uint32_t p) {
    return __builtin_bit_cast(float, p << 16);
}
__device__ __forceinline__ float unhi(uint32_t p) {
    return __builtin_bit_cast(float, p & 0xFFFF0000u);
}

__global__ __launch_bounds__(T_, 2) void capsule_routing_kernel(
    const float* __restrict__ x,   // [B, R, I]
    const float* __restrict__ w,   // [C, R, I, O]
    float* __restrict__ out)       // [B, C, O]
{
    const int wg   = blockIdx.x;       // natural order; c-major
    const int c    = wg >> 6;          // 64 b-quads per c
    const int b0   = (wg & 63) * BPB;
    const int tid  = threadIdx.x;
    const int lane = tid & 63;
    const int wid  = tid >> 6;
    const int oq   = tid & 3;          // owns outputs [4*oq, 4*oq+4)
    const int rl   = tid >> 2;         // route-node slot within pass [0,128)

    __shared__ float sred[BPB][NW][4][4];  // per-wave partial s by o-quad
    __shared__ float zred[BPB][NW];        // per-wave partial Z
    __shared__ float vsum[BPB][O_];        // running sum of v over iterations

    uint32_t up[BPB][KPT][2];   // u as packed bf16 pairs: 72 VGPR

    if (tid < BPB * O_) vsum[tid >> 4][tid & 15] = 0.f;

    // ---- u[bb][r, 4oq..4oq+3] = x[b0+bb,r,:] @ W[c,r,:,4oq..4oq+3] ----
    #pragma unroll
    for (int k = 0; k < KPT; ++k) {
        const int r = k * RPP + rl;
        // hold this r's W column-quad: 8 x float4 (dwordx4, quad covers 64B line)
        const float4* wb4 = (const float4*)(w + ((size_t)c * R_ + r) * (I_ * O_));
        float4 W0 = wb4[0 * 4 + oq], W1 = wb4[1 * 4 + oq];
        float4 W2 = wb4[2 * 4 + oq], W3 = wb4[3 * 4 + oq];
        float4 W4 = wb4[4 * 4 + oq], W5 = wb4[5 * 4 + oq];
        float4 W6 = wb4[6 * 4 + oq], W7 = wb4[7 * 4 + oq];
        #pragma unroll
        for (int bb = 0; bb < BPB; ++bb) {
            const float4* xp = (const float4*)(x + ((size_t)(b0 + bb) * R_ + r) * I_);
            const float4 xa = xp[0];
            const float4 xb = xp[1];
            float a0, a1, a2, a3;
            a0 = xa.x * W0.x; a1 = xa.x * W0.y; a2 = xa.x * W0.z; a3 = xa.x * W0.w;
            a0 += xa.y * W1.x; a1 += xa.y * W1.y; a2 += xa.y * W1.z; a3 += xa.y * W1.w;
            a0 += xa.z * W2.x; a1 += xa.z * W2.y; a2 += xa.z * W2.z; a3 += xa.z * W2.w;
            a0 += xa.w * W3.x; a1 += xa.w * W3.y; a2 += xa.w * W3.z; a3 += xa.w * W3.w;
            a0 += xb.x * W4.x; a1 += xb.x * W4.y; a2 += xb.x * W4.z; a3 += xb.x * W4.w;
            a0 += xb.y * W5.x; a1 += xb.y * W5.y; a2 += xb.y * W5.z; a3 += xb.y * W5.w;
            a0 += xb.z * W6.x; a1 += xb.z * W6.y; a2 += xb.z * W6.z; a3 += xb.z * W6.w;
            a0 += xb.w * W7.x; a1 += xb.w * W7.y; a2 += xb.w * W7.z; a3 += xb.w * W7.w;
            up[bb][k][0] = pack2(a0, a1);
            up[bb][k][1] = pack2(a2, a3);
        }
    }
    __syncthreads();   // vsum init visible to all

    // ---- routing iterations (logits recomputed from vsum; no logit state) ----
    #pragma unroll
    for (int it = 0; it < NITER; ++it) {
        float zz[BPB], ss[BPB][4];
        #pragma unroll
        for (int bb = 0; bb < BPB; ++bb) {
            float4 vs = make_float4(0.f, 0.f, 0.f, 0.f);
            if (it > 0) vs = *(const float4*)&vsum[bb][oq * 4];
            float z = 0.f, s0 = 0.f, s1 = 0.f, s2 = 0.f, s3 = 0.f;
            #pragma unroll
            for (int k = 0; k < KPT; ++k) {
                const float u0 = unlo(up[bb][k][0]);
                const float u1 = unhi(up[bb][k][0]);
                const float u2 = unlo(up[bb][k][1]);
                const float u3 = unhi(up[bb][k][1]);
                float e;
                if (it == 0) {
                    e = 1.f;   // logits are 0 at iteration 0
                } else {
                    float d = u0 * vs.x + u1 * vs.y + u2 * vs.z + u3 * vs.w;
                    d += __shfl_xor(d, 1);   // quad-reduce over the 4 o-quads
                    d += __shfl_xor(d, 2);
                    e = __expf(d);
                }
                z += e;
                s0 += e * u0; s1 += e * u1; s2 += e * u2; s3 += e * u3;
            }
            zz[bb] = z;
            ss[bb][0] = s0; ss[bb][1] = s1; ss[bb][2] = s2; ss[bb][3] = s3;
        }
        // wave butterfly over the 16 quads (oq kept separate)
        #pragma unroll
        for (int off = 4; off <= 32; off <<= 1) {
            #pragma unroll
            for (int bb = 0; bb < BPB; ++bb) {
                zz[bb] += __shfl_xor(zz[bb], off);
                ss[bb][0] += __shfl_xor(ss[bb][0], off);
                ss[bb][1] += __shfl_xor(ss[bb][1], off);
                ss[bb][2] += __shfl_xor(ss[bb][2], off);
                ss[bb][3] += __shfl_xor(ss[bb][3], off);
            }
        }
        if (lane < 4) {   // lane == oq here
            #pragma unroll
            for (int bb = 0; bb < BPB; ++bb) {
                sred[bb][wid][lane][0] = ss[bb][0];
                sred[bb][wid][lane][1] = ss[bb][1];
                sred[bb][wid][lane][2] = ss[bb][2];
                sred[bb][wid][lane][3] = ss[bb][3];
                if (lane == 0) zred[bb][wid] = zz[bb];
            }
        }
        __syncthreads();

        // wave 0 finalizes all 4 batches: lane = 16*bb + o
        if (wid == 0) {
            const int bb = lane >> 4;
            const int o  = lane & 15;
            float S = 0.f, Z = 0.f;
            #pragma unroll
            for (int wv = 0; wv < NW; ++wv) {
                S += sred[bb][wv][o >> 2][o & 3];
                Z += zred[bb][wv];
            }
            const float inv = 1.f / Z;
            const float svn = S * inv;
            float p = svn * svn;   // butterfly within 16-lane group -> |s|^2
            p += __shfl_xor(p, 1);
            p += __shfl_xor(p, 2);
            p += __shfl_xor(p, 4);
            p += __shfl_xor(p, 8);
            const float scale = sqrtf(p) / (1.f + p);
            const float vf = svn * scale;
            vsum[bb][o] += vf;     // same wave (wave0) wrote the init -> no race
            if (it == NITER - 1)
                out[((size_t)(b0 + bb) * C_ + c) * O_ + o] = vf;
        }
        if (it != NITER - 1) __syncthreads();   // vsum update visible to all
    }
}

extern "C" void kernel_launch(void* const* d_in, const int* in_sizes, int n_in,
                              void* d_out, int out_size, void* d_ws, size_t ws_size,
                              hipStream_t stream) {
    const float* x = (const float*)d_in[0];
    const float* w = (const float*)d_in[1];
    float* out = (float*)d_out;
    capsule_routing_kernel<<<dim3(C_ * (B_ / BPB)), dim3(T_), 0, stream>>>(x, w, out);
}

// Round 11
// 65.450 us; speedup vs baseline: 1.9503x; 1.0783x over previous
//
#include <hip/hip_runtime.h>
#include <stdint.h>

// CapsuleLayer dynamic routing — round 11: two-kernel split, u materialized bf16.
// x: [B=256, R=1152, I=8] f32; W: [C=10, R=1152, I=8, O=16] f32
// out: v = [B, C, 1, 1, O=16] f32
//
// Ten-round triangulation: the FUSED design is pinched between two walls:
//   - amortizing W across batches needs per-thread u state -> kills residency
//     (r10: 116 VGPR, 6 waves/CU, latency-bound at 70us), while
//   - high residency forces W re-reads -> L2-BW-bound (r3: 58% occ but 1.9GB
//     L2 traffic = 73% of the 34.5TB/s ceiling, 75us).
// Escape: materialize u ONCE (bf16, 94MB, L3-resident) and route from it.
//   K1 (u-GEMM): W read ~47MB total (vs 377-1500MB), coalesced bf16 writes.
//   K2 (routing): u loaded once into 18 packed VGPRs, 3 iters in-register,
//                 ~45 VGPR -> 4 blocks/CU, trivially latency-tolerant.
// Fallback: if ws_size < 94MB, run the round-10 fused kernel (proven, 70us).

#define B_ 256
#define C_ 10
#define R_ 1152
#define I_ 8
#define O_ 16
#define T_ 512
#define KPT 9            // R chunks of 128
#define NW 8
#define NITER 3

__device__ __forceinline__ uint32_t bf16_rn(float f) {
    uint32_t u = __builtin_bit_cast(uint32_t, f);
    return (u + 0x7FFFu + ((u >> 16) & 1u)) >> 16;
}
__device__ __forceinline__ uint32_t pack2(float lo, float hi) {
    return bf16_rn(lo) | (bf16_rn(hi) << 16);
}
__device__ __forceinline__ float unlo(uint32_t p) {
    return __builtin_bit_cast(float, p << 16);
}
__device__ __forceinline__ float unhi(uint32_t p) {
    return __builtin_bit_cast(float, p & 0xFFFF0000u);
}

// ---------------- K1: u[b,c,r,:] = x[b,r,:] @ W[c,r,:,:]  (bf16 packed) ----
// grid 720 = c(10) x kchunk(9) x btile(8). T=512; thread = (rl=tid>>2, oq=tid&3).
// W[c, kchunk] chunk lives in 32 VGPRs, reused for 32 batches.
// u layout: uint2[ ((b*C + c)*KPT + k)*512 + tid ]  -> K2 reads contiguously.
__global__ __launch_bounds__(T_, 2) void caps_u_kernel(
    const float* __restrict__ x,
    const float* __restrict__ w,
    uint2* __restrict__ u)
{
    const int bx  = blockIdx.x;
    const int c   = bx / 72;
    const int kc  = (bx % 72) >> 3;
    const int bt  = bx & 7;
    const int tid = threadIdx.x;
    const int oq  = tid & 3;
    const int rl  = tid >> 2;
    const int r   = kc * 128 + rl;

    const float4* wb4 = (const float4*)(w + ((size_t)c * R_ + r) * (I_ * O_));
    const float4 W0 = wb4[0 * 4 + oq], W1 = wb4[1 * 4 + oq];
    const float4 W2 = wb4[2 * 4 + oq], W3 = wb4[3 * 4 + oq];
    const float4 W4 = wb4[4 * 4 + oq], W5 = wb4[5 * 4 + oq];
    const float4 W6 = wb4[6 * 4 + oq], W7 = wb4[7 * 4 + oq];

    #pragma unroll 4
    for (int bb = 0; bb < 32; ++bb) {
        const int b = bt * 32 + bb;
        const float4* xp = (const float4*)(x + ((size_t)b * R_ + r) * I_);
        const float4 xa = xp[0];
        const float4 xb = xp[1];
        float a0, a1, a2, a3;
        a0 = xa.x * W0.x; a1 = xa.x * W0.y; a2 = xa.x * W0.z; a3 = xa.x * W0.w;
        a0 += xa.y * W1.x; a1 += xa.y * W1.y; a2 += xa.y * W1.z; a3 += xa.y * W1.w;
        a0 += xa.z * W2.x; a1 += xa.z * W2.y; a2 += xa.z * W2.z; a3 += xa.z * W2.w;
        a0 += xa.w * W3.x; a1 += xa.w * W3.y; a2 += xa.w * W3.z; a3 += xa.w * W3.w;
        a0 += xb.x * W4.x; a1 += xb.x * W4.y; a2 += xb.x * W4.z; a3 += xb.x * W4.w;
        a0 += xb.y * W5.x; a1 += xb.y * W5.y; a2 += xb.y * W5.z; a3 += xb.y * W5.w;
        a0 += xb.z * W6.x; a1 += xb.z * W6.y; a2 += xb.z * W6.z; a3 += xb.z * W6.w;
        a0 += xb.w * W7.x; a1 += xb.w * W7.y; a2 += xb.w * W7.z; a3 += xb.w * W7.w;
        u[(((size_t)b * C_ + c) * KPT + kc) * T_ + tid] =
            make_uint2(pack2(a0, a1), pack2(a2, a3));
    }
}

// ---------------- K2: routing from materialized u ----------------
// One block per (b,c); wg = b*C + c matches u layout -> sequential reads.
// Thread loads its 9 uint2 (36 bf16 u-values) once; 3 iterations in-register.
// vsum trick: no logit registers; logit = u . (running sum of v), exp(0)=1 at it0.
__global__ __launch_bounds__(T_, 2) void caps_route_kernel(
    const uint2* __restrict__ u,
    float* __restrict__ out)
{
    const int wg   = blockIdx.x;       // = b*C + c
    const int tid  = threadIdx.x;
    const int lane = tid & 63;
    const int wid  = tid >> 6;
    const int oq   = tid & 3;

    __shared__ float sred[NW][4][4];
    __shared__ float zred[NW];
    __shared__ float vsum[O_];

    uint2 up[KPT];
    #pragma unroll
    for (int k = 0; k < KPT; ++k)
        up[k] = u[((size_t)wg * KPT + k) * T_ + tid];

    if (tid < O_) vsum[tid] = 0.f;
    __syncthreads();

    #pragma unroll
    for (int it = 0; it < NITER; ++it) {
        float4 vs = make_float4(0.f, 0.f, 0.f, 0.f);
        if (it > 0) vs = *(const float4*)&vsum[oq * 4];
        float z = 0.f, s0 = 0.f, s1 = 0.f, s2 = 0.f, s3 = 0.f;
        #pragma unroll
        for (int k = 0; k < KPT; ++k) {
            const float u0 = unlo(up[k].x);
            const float u1 = unhi(up[k].x);
            const float u2 = unlo(up[k].y);
            const float u3 = unhi(up[k].y);
            float e;
            if (it == 0) {
                e = 1.f;
            } else {
                float d = u0 * vs.x + u1 * vs.y + u2 * vs.z + u3 * vs.w;
                d += __shfl_xor(d, 1);    // quad-reduce over the 4 o-quads
                d += __shfl_xor(d, 2);
                e = __expf(d);
            }
            z += e;
            s0 += e * u0; s1 += e * u1; s2 += e * u2; s3 += e * u3;
        }
        #pragma unroll
        for (int off = 4; off <= 32; off <<= 1) {
            z  += __shfl_xor(z, off);
            s0 += __shfl_xor(s0, off);
            s1 += __shfl_xor(s1, off);
            s2 += __shfl_xor(s2, off);
            s3 += __shfl_xor(s3, off);
        }
        if (lane < 4) {   // lane == oq
            sred[wid][lane][0] = s0;
            sred[wid][lane][1] = s1;
            sred[wid][lane][2] = s2;
            sred[wid][lane][3] = s3;
            if (lane == 0) zred[wid] = z;
        }
        __syncthreads();

        if (wid == 0 && lane < O_) {
            float S = 0.f, Z = 0.f;
            #pragma unroll
            for (int wv = 0; wv < NW; ++wv) {
                S += sred[wv][lane >> 2][lane & 3];
                Z += zred[wv];
            }
            const float inv = 1.f / Z;
            const float svn = S * inv;
            float p = svn * svn;
            p += __shfl_xor(p, 1);
            p += __shfl_xor(p, 2);
            p += __shfl_xor(p, 4);
            p += __shfl_xor(p, 8);
            const float scale = sqrtf(p) / (1.f + p);
            const float vf = svn * scale;
            vsum[lane] += vf;
            if (it == NITER - 1)
                out[(size_t)wg * O_ + lane] = vf;
        }
        if (it != NITER - 1) __syncthreads();
    }
}

// ---------------- Fallback: round-10 fused kernel (proven) ----------------
#define BPB 4
#define RPP 128

__global__ __launch_bounds__(T_, 2) void capsule_fused_kernel(
    const float* __restrict__ x,
    const float* __restrict__ w,
    float* __restrict__ out)
{
    const int wg   = blockIdx.x;
    const int c    = wg >> 6;
    const int b0   = (wg & 63) * BPB;
    const int tid  = threadIdx.x;
    const int lane = tid & 63;
    const int wid  = tid >> 6;
    const int oq   = tid & 3;
    const int rl   = tid >> 2;

    __shared__ float sred[BPB][NW][4][4];
    __shared__ float zred[BPB][NW];
    __shared__ float vsum[BPB][O_];

    uint32_t up[BPB][KPT][2];

    if (tid < BPB * O_) vsum[tid >> 4][tid & 15] = 0.f;

    #pragma unroll
    for (int k = 0; k < KPT; ++k) {
        const int r = k * RPP + rl;
        const float4* wb4 = (const float4*)(w + ((size_t)c * R_ + r) * (I_ * O_));
        float4 W0 = wb4[0 * 4 + oq], W1 = wb4[1 * 4 + oq];
        float4 W2 = wb4[2 * 4 + oq], W3 = wb4[3 * 4 + oq];
        float4 W4 = wb4[4 * 4 + oq], W5 = wb4[5 * 4 + oq];
        float4 W6 = wb4[6 * 4 + oq], W7 = wb4[7 * 4 + oq];
        #pragma unroll
        for (int bb = 0; bb < BPB; ++bb) {
            const float4* xp = (const float4*)(x + ((size_t)(b0 + bb) * R_ + r) * I_);
            const float4 xa = xp[0];
            const float4 xb = xp[1];
            float a0, a1, a2, a3;
            a0 = xa.x * W0.x; a1 = xa.x * W0.y; a2 = xa.x * W0.z; a3 = xa.x * W0.w;
            a0 += xa.y * W1.x; a1 += xa.y * W1.y; a2 += xa.y * W1.z; a3 += xa.y * W1.w;
            a0 += xa.z * W2.x; a1 += xa.z * W2.y; a2 += xa.z * W2.z; a3 += xa.z * W2.w;
            a0 += xa.w * W3.x; a1 += xa.w * W3.y; a2 += xa.w * W3.z; a3 += xa.w * W3.w;
            a0 += xb.x * W4.x; a1 += xb.x * W4.y; a2 += xb.x * W4.z; a3 += xb.x * W4.w;
            a0 += xb.y * W5.x; a1 += xb.y * W5.y; a2 += xb.y * W5.z; a3 += xb.y * W5.w;
            a0 += xb.z * W6.x; a1 += xb.z * W6.y; a2 += xb.z * W6.z; a3 += xb.z * W6.w;
            a0 += xb.w * W7.x; a1 += xb.w * W7.y; a2 += xb.w * W7.z; a3 += xb.w * W7.w;
            up[bb][k][0] = pack2(a0, a1);
            up[bb][k][1] = pack2(a2, a3);
        }
    }
    __syncthreads();

    #pragma unroll
    for (int it = 0; it < NITER; ++it) {
        float zz[BPB], ss[BPB][4];
        #pragma unroll
        for (int bb = 0; bb < BPB; ++bb) {
            float4 vs = make_float4(0.f, 0.f, 0.f, 0.f);
            if (it > 0) vs = *(const float4*)&vsum[bb][oq * 4];
            float z = 0.f, s0 = 0.f, s1 = 0.f, s2 = 0.f, s3 = 0.f;
            #pragma unroll
            for (int k = 0; k < KPT; ++k) {
                const float u0 = unlo(up[bb][k][0]);
                const float u1 = unhi(up[bb][k][0]);
                const float u2 = unlo(up[bb][k][1]);
                const float u3 = unhi(up[bb][k][1]);
                float e;
                if (it == 0) {
                    e = 1.f;
                } else {
                    float d = u0 * vs.x + u1 * vs.y + u2 * vs.z + u3 * vs.w;
                    d += __shfl_xor(d, 1);
                    d += __shfl_xor(d, 2);
                    e = __expf(d);
                }
                z += e;
                s0 += e * u0; s1 += e * u1; s2 += e * u2; s3 += e * u3;
            }
            zz[bb] = z;
            ss[bb][0] = s0; ss[bb][1] = s1; ss[bb][2] = s2; ss[bb][3] = s3;
        }
        #pragma unroll
        for (int off = 4; off <= 32; off <<= 1) {
            #pragma unroll
            for (int bb = 0; bb < BPB; ++bb) {
                zz[bb] += __shfl_xor(zz[bb], off);
                ss[bb][0] += __shfl_xor(ss[bb][0], off);
                ss[bb][1] += __shfl_xor(ss[bb][1], off);
                ss[bb][2] += __shfl_xor(ss[bb][2], off);
                ss[bb][3] += __shfl_xor(ss[bb][3], off);
            }
        }
        if (lane < 4) {
            #pragma unroll
            for (int bb = 0; bb < BPB; ++bb) {
                sred[bb][wid][lane][0] = ss[bb][0];
                sred[bb][wid][lane][1] = ss[bb][1];
                sred[bb][wid][lane][2] = ss[bb][2];
                sred[bb][wid][lane][3] = ss[bb][3];
                if (lane == 0) zred[bb][wid] = zz[bb];
            }
        }
        __syncthreads();

        if (wid == 0) {
            const int bb = lane >> 4;
            const int o  = lane & 15;
            float S = 0.f, Z = 0.f;
            #pragma unroll
            for (int wv = 0; wv < NW; ++wv) {
                S += sred[bb][wv][o >> 2][o & 3];
                Z += zred[bb][wv];
            }
            const float inv = 1.f / Z;
            const float svn = S * inv;
            float p = svn * svn;
            p += __shfl_xor(p, 1);
            p += __shfl_xor(p, 2);
            p += __shfl_xor(p, 4);
            p += __shfl_xor(p, 8);
            const float scale = sqrtf(p) / (1.f + p);
            const float vf = svn * scale;
            vsum[bb][o] += vf;
            if (it == NITER - 1)
                out[((size_t)(b0 + bb) * C_ + c) * O_ + o] = vf;
        }
        if (it != NITER - 1) __syncthreads();
    }
}

extern "C" void kernel_launch(void* const* d_in, const int* in_sizes, int n_in,
                              void* d_out, int out_size, void* d_ws, size_t ws_size,
                              hipStream_t stream) {
    const float* x = (const float*)d_in[0];
    const float* w = (const float*)d_in[1];
    float* out = (float*)d_out;

    const size_t u_bytes = (size_t)B_ * C_ * KPT * T_ * 8;   // 94,371,840
    if (ws_size >= u_bytes) {
        uint2* u = (uint2*)d_ws;
        caps_u_kernel<<<dim3(C_ * KPT * 8), dim3(T_), 0, stream>>>(x, w, u);
        caps_route_kernel<<<dim3(B_ * C_), dim3(T_), 0, stream>>>(u, out);
    } else {
        capsule_fused_kernel<<<dim3(C_ * (B_ / BPB)), dim3(T_), 0, stream>>>(x, w, out);
    }
}

// Round 12
// 61.712 us; speedup vs baseline: 2.0684x; 1.0606x over previous
//
#include <hip/hip_runtime.h>
#include <stdint.h>

// CapsuleLayer dynamic routing — round 12: split kernels; K1 occupancy fix.
// x: [B=256, R=1152, I=8] f32; W: [C=10, R=1152, I=8, O=16] f32
// out: v = [B, C, 1, 1, O=16] f32
//
// Round-11: split (u materialized bf16, 94MB) = 65us; K1 48us @ 25% occupancy
// (720 blocks, LB(512,2)) writing at only 1.9TB/s -> parallelism-starved.
// Round-12: K1 grid 720 -> 2880 (8 batches/block), LB(512,3) (3 blocks/CU,
// ~85 VGPR cap; K1 uses ~60), K2 LB(512,4) (uses ~40 VGPR, 64 cap).
// u layout unchanged: uint2[ ((b*C + c)*KPT + kc)*512 + tid ].
// Fallback: round-10 fused kernel if ws too small.

#define B_ 256
#define C_ 10
#define R_ 1152
#define I_ 8
#define O_ 16
#define T_ 512
#define KPT 9            // R chunks of 128
#define NW 8
#define NITER 3

__device__ __forceinline__ uint32_t bf16_rn(float f) {
    uint32_t u = __builtin_bit_cast(uint32_t, f);
    return (u + 0x7FFFu + ((u >> 16) & 1u)) >> 16;
}
__device__ __forceinline__ uint32_t pack2(float lo, float hi) {
    return bf16_rn(lo) | (bf16_rn(hi) << 16);
}
__device__ __forceinline__ float unlo(uint32_t p) {
    return __builtin_bit_cast(float, p << 16);
}
__device__ __forceinline__ float unhi(uint32_t p) {
    return __builtin_bit_cast(float, p & 0xFFFF0000u);
}

// ---------------- K1: u[b,c,r,:] = x[b,r,:] @ W[c,r,:,:]  (bf16 packed) ----
// grid 2880 = c(10) x kchunk(9) x btile(32). T=512; thread = (rl=tid>>2, oq=tid&3).
// W[c,kchunk] chunk in 32 VGPRs, reused for 8 batches (8 independent chains).
__global__ __launch_bounds__(T_, 3) void caps_u_kernel(
    const float* __restrict__ x,
    const float* __restrict__ w,
    uint2* __restrict__ u)
{
    const int bx  = blockIdx.x;
    const int c   = bx / 288;
    const int kc  = (bx % 288) >> 5;
    const int bt  = bx & 31;
    const int tid = threadIdx.x;
    const int oq  = tid & 3;
    const int rl  = tid >> 2;
    const int r   = kc * 128 + rl;

    const float4* wb4 = (const float4*)(w + ((size_t)c * R_ + r) * (I_ * O_));
    const float4 W0 = wb4[0 * 4 + oq], W1 = wb4[1 * 4 + oq];
    const float4 W2 = wb4[2 * 4 + oq], W3 = wb4[3 * 4 + oq];
    const float4 W4 = wb4[4 * 4 + oq], W5 = wb4[5 * 4 + oq];
    const float4 W6 = wb4[6 * 4 + oq], W7 = wb4[7 * 4 + oq];

    #pragma unroll 4
    for (int bb = 0; bb < 8; ++bb) {
        const int b = bt * 8 + bb;
        const float4* xp = (const float4*)(x + ((size_t)b * R_ + r) * I_);
        const float4 xa = xp[0];
        const float4 xb = xp[1];
        float a0, a1, a2, a3;
        a0 = xa.x * W0.x; a1 = xa.x * W0.y; a2 = xa.x * W0.z; a3 = xa.x * W0.w;
        a0 += xa.y * W1.x; a1 += xa.y * W1.y; a2 += xa.y * W1.z; a3 += xa.y * W1.w;
        a0 += xa.z * W2.x; a1 += xa.z * W2.y; a2 += xa.z * W2.z; a3 += xa.z * W2.w;
        a0 += xa.w * W3.x; a1 += xa.w * W3.y; a2 += xa.w * W3.z; a3 += xa.w * W3.w;
        a0 += xb.x * W4.x; a1 += xb.x * W4.y; a2 += xb.x * W4.z; a3 += xb.x * W4.w;
        a0 += xb.y * W5.x; a1 += xb.y * W5.y; a2 += xb.y * W5.z; a3 += xb.y * W5.w;
        a0 += xb.z * W6.x; a1 += xb.z * W6.y; a2 += xb.z * W6.z; a3 += xb.z * W6.w;
        a0 += xb.w * W7.x; a1 += xb.w * W7.y; a2 += xb.w * W7.z; a3 += xb.w * W7.w;
        u[(((size_t)b * C_ + c) * KPT + kc) * T_ + tid] =
            make_uint2(pack2(a0, a1), pack2(a2, a3));
    }
}

// ---------------- K2: routing from materialized u ----------------
// One block per (b,c); wg = b*C + c matches u layout -> sequential reads.
// Thread loads its 9 uint2 (36 bf16 u-values) once; 3 iterations in-register.
// vsum trick: no logit registers; logit = u . (running sum of v), exp(0)=1 at it0.
__global__ __launch_bounds__(T_, 4) void caps_route_kernel(
    const uint2* __restrict__ u,
    float* __restrict__ out)
{
    const int wg   = blockIdx.x;       // = b*C + c
    const int tid  = threadIdx.x;
    const int lane = tid & 63;
    const int wid  = tid >> 6;
    const int oq   = tid & 3;

    __shared__ float sred[NW][4][4];
    __shared__ float zred[NW];
    __shared__ float vsum[O_];

    uint2 up[KPT];
    #pragma unroll
    for (int k = 0; k < KPT; ++k)
        up[k] = u[((size_t)wg * KPT + k) * T_ + tid];

    if (tid < O_) vsum[tid] = 0.f;
    __syncthreads();

    #pragma unroll
    for (int it = 0; it < NITER; ++it) {
        float4 vs = make_float4(0.f, 0.f, 0.f, 0.f);
        if (it > 0) vs = *(const float4*)&vsum[oq * 4];
        float z = 0.f, s0 = 0.f, s1 = 0.f, s2 = 0.f, s3 = 0.f;
        #pragma unroll
        for (int k = 0; k < KPT; ++k) {
            const float u0 = unlo(up[k].x);
            const float u1 = unhi(up[k].x);
            const float u2 = unlo(up[k].y);
            const float u3 = unhi(up[k].y);
            float e;
            if (it == 0) {
                e = 1.f;
            } else {
                float d = u0 * vs.x + u1 * vs.y + u2 * vs.z + u3 * vs.w;
                d += __shfl_xor(d, 1);    // quad-reduce over the 4 o-quads
                d += __shfl_xor(d, 2);
                e = __expf(d);
            }
            z += e;
            s0 += e * u0; s1 += e * u1; s2 += e * u2; s3 += e * u3;
        }
        #pragma unroll
        for (int off = 4; off <= 32; off <<= 1) {
            z  += __shfl_xor(z, off);
            s0 += __shfl_xor(s0, off);
            s1 += __shfl_xor(s1, off);
            s2 += __shfl_xor(s2, off);
            s3 += __shfl_xor(s3, off);
        }
        if (lane < 4) {   // lane == oq
            sred[wid][lane][0] = s0;
            sred[wid][lane][1] = s1;
            sred[wid][lane][2] = s2;
            sred[wid][lane][3] = s3;
            if (lane == 0) zred[wid] = z;
        }
        __syncthreads();

        if (wid == 0 && lane < O_) {
            float S = 0.f, Z = 0.f;
            #pragma unroll
            for (int wv = 0; wv < NW; ++wv) {
                S += sred[wv][lane >> 2][lane & 3];
                Z += zred[wv];
            }
            const float inv = 1.f / Z;
            const float svn = S * inv;
            float p = svn * svn;
            p += __shfl_xor(p, 1);
            p += __shfl_xor(p, 2);
            p += __shfl_xor(p, 4);
            p += __shfl_xor(p, 8);
            const float scale = sqrtf(p) / (1.f + p);
            const float vf = svn * scale;
            vsum[lane] += vf;
            if (it == NITER - 1)
                out[(size_t)wg * O_ + lane] = vf;
        }
        if (it != NITER - 1) __syncthreads();
    }
}

// ---------------- Fallback: round-10 fused kernel (proven) ----------------
#define BPB 4
#define RPP 128

__global__ __launch_bounds__(T_, 2) void capsule_fused_kernel(
    const float* __restrict__ x,
    const float* __restrict__ w,
    float* __restrict__ out)
{
    const int wg   = blockIdx.x;
    const int c    = wg >> 6;
    const int b0   = (wg & 63) * BPB;
    const int tid  = threadIdx.x;
    const int lane = tid & 63;
    const int wid  = tid >> 6;
    const int oq   = tid & 3;
    const int rl   = tid >> 2;

    __shared__ float sred[BPB][NW][4][4];
    __shared__ float zred[BPB][NW];
    __shared__ float vsum[BPB][O_];

    uint32_t up[BPB][KPT][2];

    if (tid < BPB * O_) vsum[tid >> 4][tid & 15] = 0.f;

    #pragma unroll
    for (int k = 0; k < KPT; ++k) {
        const int r = k * RPP + rl;
        const float4* wb4 = (const float4*)(w + ((size_t)c * R_ + r) * (I_ * O_));
        float4 W0 = wb4[0 * 4 + oq], W1 = wb4[1 * 4 + oq];
        float4 W2 = wb4[2 * 4 + oq], W3 = wb4[3 * 4 + oq];
        float4 W4 = wb4[4 * 4 + oq], W5 = wb4[5 * 4 + oq];
        float4 W6 = wb4[6 * 4 + oq], W7 = wb4[7 * 4 + oq];
        #pragma unroll
        for (int bb = 0; bb < BPB; ++bb) {
            const float4* xp = (const float4*)(x + ((size_t)(b0 + bb) * R_ + r) * I_);
            const float4 xa = xp[0];
            const float4 xb = xp[1];
            float a0, a1, a2, a3;
            a0 = xa.x * W0.x; a1 = xa.x * W0.y; a2 = xa.x * W0.z; a3 = xa.x * W0.w;
            a0 += xa.y * W1.x; a1 += xa.y * W1.y; a2 += xa.y * W1.z; a3 += xa.y * W1.w;
            a0 += xa.z * W2.x; a1 += xa.z * W2.y; a2 += xa.z * W2.z; a3 += xa.z * W2.w;
            a0 += xa.w * W3.x; a1 += xa.w * W3.y; a2 += xa.w * W3.z; a3 += xa.w * W3.w;
            a0 += xb.x * W4.x; a1 += xb.x * W4.y; a2 += xb.x * W4.z; a3 += xb.x * W4.w;
            a0 += xb.y * W5.x; a1 += xb.y * W5.y; a2 += xb.y * W5.z; a3 += xb.y * W5.w;
            a0 += xb.z * W6.x; a1 += xb.z * W6.y; a2 += xb.z * W6.z; a3 += xb.z * W6.w;
            a0 += xb.w * W7.x; a1 += xb.w * W7.y; a2 += xb.w * W7.z; a3 += xb.w * W7.w;
            up[bb][k][0] = pack2(a0, a1);
            up[bb][k][1] = pack2(a2, a3);
        }
    }
    __syncthreads();

    #pragma unroll
    for (int it = 0; it < NITER; ++it) {
        float zz[BPB], ss[BPB][4];
        #pragma unroll
        for (int bb = 0; bb < BPB; ++bb) {
            float4 vs = make_float4(0.f, 0.f, 0.f, 0.f);
            if (it > 0) vs = *(const float4*)&vsum[bb][oq * 4];
            float z = 0.f, s0 = 0.f, s1 = 0.f, s2 = 0.f, s3 = 0.f;
            #pragma unroll
            for (int k = 0; k < KPT; ++k) {
                const float u0 = unlo(up[bb][k][0]);
                const float u1 = unhi(up[bb][k][0]);
                const float u2 = unlo(up[bb][k][1]);
                const float u3 = unhi(up[bb][k][1]);
                float e;
                if (it == 0) {
                    e = 1.f;
                } else {
                    float d = u0 * vs.x + u1 * vs.y + u2 * vs.z + u3 * vs.w;
                    d += __shfl_xor(d, 1);
                    d += __shfl_xor(d, 2);
                    e = __expf(d);
                }
                z += e;
                s0 += e * u0; s1 += e * u1; s2 += e * u2; s3 += e * u3;
            }
            zz[bb] = z;
            ss[bb][0] = s0; ss[bb][1] = s1; ss[bb][2] = s2; ss[bb][3] = s3;
        }
        #pragma unroll
        for (int off = 4; off <= 32; off <<= 1) {
            #pragma unroll
            for (int bb = 0; bb < BPB; ++bb) {
                zz[bb] += __shfl_xor(zz[bb], off);
                ss[bb][0] += __shfl_xor(ss[bb][0], off);
                ss[bb][1] += __shfl_xor(ss[bb][1], off);
                ss[bb][2] += __shfl_xor(ss[bb][2], off);
                ss[bb][3] += __shfl_xor(ss[bb][3], off);
            }
        }
        if (lane < 4) {
            #pragma unroll
            for (int bb = 0; bb < BPB; ++bb) {
                sred[bb][wid][lane][0] = ss[bb][0];
                sred[bb][wid][lane][1] = ss[bb][1];
                sred[bb][wid][lane][2] = ss[bb][2];
                sred[bb][wid][lane][3] = ss[bb][3];
                if (lane == 0) zred[bb][wid] = zz[bb];
            }
        }
        __syncthreads();

        if (wid == 0) {
            const int bb = lane >> 4;
            const int o  = lane & 15;
            float S = 0.f, Z = 0.f;
            #pragma unroll
            for (int wv = 0; wv < NW; ++wv) {
                S += sred[bb][wv][o >> 2][o & 3];
                Z += zred[bb][wv];
            }
            const float inv = 1.f / Z;
            const float svn = S * inv;
            float p = svn * svn;
            p += __shfl_xor(p, 1);
            p += __shfl_xor(p, 2);
            p += __shfl_xor(p, 4);
            p += __shfl_xor(p, 8);
            const float scale = sqrtf(p) / (1.f + p);
            const float vf = svn * scale;
            vsum[bb][o] += vf;
            if (it == NITER - 1)
                out[((size_t)(b0 + bb) * C_ + c) * O_ + o] = vf;
        }
        if (it != NITER - 1) __syncthreads();
    }
}

extern "C" void kernel_launch(void* const* d_in, const int* in_sizes, int n_in,
                              void* d_out, int out_size, void* d_ws, size_t ws_size,
                              hipStream_t stream) {
    const float* x = (const float*)d_in[0];
    const float* w = (const float*)d_in[1];
    float* out = (float*)d_out;

    const size_t u_bytes = (size_t)B_ * C_ * KPT * T_ * 8;   // 94,371,840
    if (ws_size >= u_bytes) {
        uint2* u = (uint2*)d_ws;
        caps_u_kernel<<<dim3(C_ * KPT * 32), dim3(T_), 0, stream>>>(x, w, u);
        caps_route_kernel<<<dim3(B_ * C_), dim3(T_), 0, stream>>>(u, out);
    } else {
        capsule_fused_kernel<<<dim3(C_ * (B_ / BPB)), dim3(T_), 0, stream>>>(x, w, out);
    }
}

// Round 13
// 60.934 us; speedup vs baseline: 2.0948x; 1.0128x over previous
//
#include <hip/hip_runtime.h>
#include <stdint.h>

// CapsuleLayer dynamic routing — round 13: pin W in VGPRs (defeat remat).
// x: [B=256, R=1152, I=8] f32; W: [C=10, R=1152, I=8, O=16] f32
// out: v = [B, C, 1, 1, O=16] f32
//
// Round-12 post-mortem: K1 reported VGPR_Count=32 -> compiler SANK the 8x
// float4 W loads into the bb loop (rematerialized each batch) -> 1.5GB of
// redundant W L2 traffic = ~43us at the 34.5TB/s L2 ceiling = K1's entire
// 41.9us. Fix: opaque inline-asm on each W component after the load; the asm
// output can't be re-derived by re-loading, so all 32 W VGPRs stay live
// across the 8-batch loop. W L2 traffic drops 8x (1.5GB -> 184MB).
// K2 already at ~5.5TB/s streaming its 94MB -> untouched.
// Fallback: round-10 fused kernel if ws too small.

#define B_ 256
#define C_ 10
#define R_ 1152
#define I_ 8
#define O_ 16
#define T_ 512
#define KPT 9            // R chunks of 128
#define NW 8
#define NITER 3

__device__ __forceinline__ uint32_t bf16_rn(float f) {
    uint32_t u = __builtin_bit_cast(uint32_t, f);
    return (u + 0x7FFFu + ((u >> 16) & 1u)) >> 16;
}
__device__ __forceinline__ uint32_t pack2(float lo, float hi) {
    return bf16_rn(lo) | (bf16_rn(hi) << 16);
}
__device__ __forceinline__ float unlo(uint32_t p) {
    return __builtin_bit_cast(float, p << 16);
}
__device__ __forceinline__ float unhi(uint32_t p) {
    return __builtin_bit_cast(float, p & 0xFFFF0000u);
}

// Opaque register pin: compiler must treat the value as produced by the asm,
// so it cannot rematerialize it by re-loading from memory.
#define PIN4(v) asm volatile("" : "+v"(v.x), "+v"(v.y), "+v"(v.z), "+v"(v.w))

// ---------------- K1: u[b,c,r,:] = x[b,r,:] @ W[c,r,:,:]  (bf16 packed) ----
// grid 2880 = c(10) x kchunk(9) x btile(32). T=512; thread = (rl=tid>>2, oq=tid&3).
// W[c,kchunk] chunk pinned in 32 VGPRs, reused for 8 batches.
__global__ __launch_bounds__(T_, 3) void caps_u_kernel(
    const float* __restrict__ x,
    const float* __restrict__ w,
    uint2* __restrict__ u)
{
    const int bx  = blockIdx.x;
    const int c   = bx / 288;
    const int kc  = (bx % 288) >> 5;
    const int bt  = bx & 31;
    const int tid = threadIdx.x;
    const int oq  = tid & 3;
    const int rl  = tid >> 2;
    const int r   = kc * 128 + rl;

    const float4* wb4 = (const float4*)(w + ((size_t)c * R_ + r) * (I_ * O_));
    float4 W0 = wb4[0 * 4 + oq], W1 = wb4[1 * 4 + oq];
    float4 W2 = wb4[2 * 4 + oq], W3 = wb4[3 * 4 + oq];
    float4 W4 = wb4[4 * 4 + oq], W5 = wb4[5 * 4 + oq];
    float4 W6 = wb4[6 * 4 + oq], W7 = wb4[7 * 4 + oq];
    PIN4(W0); PIN4(W1); PIN4(W2); PIN4(W3);
    PIN4(W4); PIN4(W5); PIN4(W6); PIN4(W7);

    #pragma unroll 4
    for (int bb = 0; bb < 8; ++bb) {
        const int b = bt * 8 + bb;
        const float4* xp = (const float4*)(x + ((size_t)b * R_ + r) * I_);
        const float4 xa = xp[0];
        const float4 xb = xp[1];
        float a0, a1, a2, a3;
        a0 = xa.x * W0.x; a1 = xa.x * W0.y; a2 = xa.x * W0.z; a3 = xa.x * W0.w;
        a0 += xa.y * W1.x; a1 += xa.y * W1.y; a2 += xa.y * W1.z; a3 += xa.y * W1.w;
        a0 += xa.z * W2.x; a1 += xa.z * W2.y; a2 += xa.z * W2.z; a3 += xa.z * W2.w;
        a0 += xa.w * W3.x; a1 += xa.w * W3.y; a2 += xa.w * W3.z; a3 += xa.w * W3.w;
        a0 += xb.x * W4.x; a1 += xb.x * W4.y; a2 += xb.x * W4.z; a3 += xb.x * W4.w;
        a0 += xb.y * W5.x; a1 += xb.y * W5.y; a2 += xb.y * W5.z; a3 += xb.y * W5.w;
        a0 += xb.z * W6.x; a1 += xb.z * W6.y; a2 += xb.z * W6.z; a3 += xb.z * W6.w;
        a0 += xb.w * W7.x; a1 += xb.w * W7.y; a2 += xb.w * W7.z; a3 += xb.w * W7.w;
        u[(((size_t)b * C_ + c) * KPT + kc) * T_ + tid] =
            make_uint2(pack2(a0, a1), pack2(a2, a3));
    }
}

// ---------------- K2: routing from materialized u ----------------
// One block per (b,c); wg = b*C + c matches u layout -> sequential reads.
// Thread loads its 9 uint2 (36 bf16 u-values) once; 3 iterations in-register.
// vsum trick: no logit registers; logit = u . (running sum of v), exp(0)=1 at it0.
__global__ __launch_bounds__(T_, 4) void caps_route_kernel(
    const uint2* __restrict__ u,
    float* __restrict__ out)
{
    const int wg   = blockIdx.x;       // = b*C + c
    const int tid  = threadIdx.x;
    const int lane = tid & 63;
    const int wid  = tid >> 6;
    const int oq   = tid & 3;

    __shared__ float sred[NW][4][4];
    __shared__ float zred[NW];
    __shared__ float vsum[O_];

    uint2 up[KPT];
    #pragma unroll
    for (int k = 0; k < KPT; ++k)
        up[k] = u[((size_t)wg * KPT + k) * T_ + tid];

    if (tid < O_) vsum[tid] = 0.f;
    __syncthreads();

    #pragma unroll
    for (int it = 0; it < NITER; ++it) {
        float4 vs = make_float4(0.f, 0.f, 0.f, 0.f);
        if (it > 0) vs = *(const float4*)&vsum[oq * 4];
        float z = 0.f, s0 = 0.f, s1 = 0.f, s2 = 0.f, s3 = 0.f;
        #pragma unroll
        for (int k = 0; k < KPT; ++k) {
            const float u0 = unlo(up[k].x);
            const float u1 = unhi(up[k].x);
            const float u2 = unlo(up[k].y);
            const float u3 = unhi(up[k].y);
            float e;
            if (it == 0) {
                e = 1.f;
            } else {
                float d = u0 * vs.x + u1 * vs.y + u2 * vs.z + u3 * vs.w;
                d += __shfl_xor(d, 1);    // quad-reduce over the 4 o-quads
                d += __shfl_xor(d, 2);
                e = __expf(d);
            }
            z += e;
            s0 += e * u0; s1 += e * u1; s2 += e * u2; s3 += e * u3;
        }
        #pragma unroll
        for (int off = 4; off <= 32; off <<= 1) {
            z  += __shfl_xor(z, off);
            s0 += __shfl_xor(s0, off);
            s1 += __shfl_xor(s1, off);
            s2 += __shfl_xor(s2, off);
            s3 += __shfl_xor(s3, off);
        }
        if (lane < 4) {   // lane == oq
            sred[wid][lane][0] = s0;
            sred[wid][lane][1] = s1;
            sred[wid][lane][2] = s2;
            sred[wid][lane][3] = s3;
            if (lane == 0) zred[wid] = z;
        }
        __syncthreads();

        if (wid == 0 && lane < O_) {
            float S = 0.f, Z = 0.f;
            #pragma unroll
            for (int wv = 0; wv < NW; ++wv) {
                S += sred[wv][lane >> 2][lane & 3];
                Z += zred[wv];
            }
            const float inv = 1.f / Z;
            const float svn = S * inv;
            float p = svn * svn;
            p += __shfl_xor(p, 1);
            p += __shfl_xor(p, 2);
            p += __shfl_xor(p, 4);
            p += __shfl_xor(p, 8);
            const float scale = sqrtf(p) / (1.f + p);
            const float vf = svn * scale;
            vsum[lane] += vf;
            if (it == NITER - 1)
                out[(size_t)wg * O_ + lane] = vf;
        }
        if (it != NITER - 1) __syncthreads();
    }
}

// ---------------- Fallback: round-10 fused kernel (proven) ----------------
#define BPB 4
#define RPP 128

__global__ __launch_bounds__(T_, 2) void capsule_fused_kernel(
    const float* __restrict__ x,
    const float* __restrict__ w,
    float* __restrict__ out)
{
    const int wg   = blockIdx.x;
    const int c    = wg >> 6;
    const int b0   = (wg & 63) * BPB;
    const int tid  = threadIdx.x;
    const int lane = tid & 63;
    const int wid  = tid >> 6;
    const int oq   = tid & 3;
    const int rl   = tid >> 2;

    __shared__ float sred[BPB][NW][4][4];
    __shared__ float zred[BPB][NW];
    __shared__ float vsum[BPB][O_];

    uint32_t up[BPB][KPT][2];

    if (tid < BPB * O_) vsum[tid >> 4][tid & 15] = 0.f;

    #pragma unroll
    for (int k = 0; k < KPT; ++k) {
        const int r = k * RPP + rl;
        const float4* wb4 = (const float4*)(w + ((size_t)c * R_ + r) * (I_ * O_));
        float4 W0 = wb4[0 * 4 + oq], W1 = wb4[1 * 4 + oq];
        float4 W2 = wb4[2 * 4 + oq], W3 = wb4[3 * 4 + oq];
        float4 W4 = wb4[4 * 4 + oq], W5 = wb4[5 * 4 + oq];
        float4 W6 = wb4[6 * 4 + oq], W7 = wb4[7 * 4 + oq];
        #pragma unroll
        for (int bb = 0; bb < BPB; ++bb) {
            const float4* xp = (const float4*)(x + ((size_t)(b0 + bb) * R_ + r) * I_);
            const float4 xa = xp[0];
            const float4 xb = xp[1];
            float a0, a1, a2, a3;
            a0 = xa.x * W0.x; a1 = xa.x * W0.y; a2 = xa.x * W0.z; a3 = xa.x * W0.w;
            a0 += xa.y * W1.x; a1 += xa.y * W1.y; a2 += xa.y * W1.z; a3 += xa.y * W1.w;
            a0 += xa.z * W2.x; a1 += xa.z * W2.y; a2 += xa.z * W2.z; a3 += xa.z * W2.w;
            a0 += xa.w * W3.x; a1 += xa.w * W3.y; a2 += xa.w * W3.z; a3 += xa.w * W3.w;
            a0 += xb.x * W4.x; a1 += xb.x * W4.y; a2 += xb.x * W4.z; a3 += xb.x * W4.w;
            a0 += xb.y * W5.x; a1 += xb.y * W5.y; a2 += xb.y * W5.z; a3 += xb.y * W5.w;
            a0 += xb.z * W6.x; a1 += xb.z * W6.y; a2 += xb.z * W6.z; a3 += xb.z * W6.w;
            a0 += xb.w * W7.x; a1 += xb.w * W7.y; a2 += xb.w * W7.z; a3 += xb.w * W7.w;
            up[bb][k][0] = pack2(a0, a1);
            up[bb][k][1] = pack2(a2, a3);
        }
    }
    __syncthreads();

    #pragma unroll
    for (int it = 0; it < NITER; ++it) {
        float zz[BPB], ss[BPB][4];
        #pragma unroll
        for (int bb = 0; bb < BPB; ++bb) {
            float4 vs = make_float4(0.f, 0.f, 0.f, 0.f);
            if (it > 0) vs = *(const float4*)&vsum[bb][oq * 4];
            float z = 0.f, s0 = 0.f, s1 = 0.f, s2 = 0.f, s3 = 0.f;
            #pragma unroll
            for (int k = 0; k < KPT; ++k) {
                const float u0 = unlo(up[bb][k][0]);
                const float u1 = unhi(up[bb][k][0]);
                const float u2 = unlo(up[bb][k][1]);
                const float u3 = unhi(up[bb][k][1]);
                float e;
                if (it == 0) {
                    e = 1.f;
                } else {
                    float d = u0 * vs.x + u1 * vs.y + u2 * vs.z + u3 * vs.w;
                    d += __shfl_xor(d, 1);
                    d += __shfl_xor(d, 2);
                    e = __expf(d);
                }
                z += e;
                s0 += e * u0; s1 += e * u1; s2 += e * u2; s3 += e * u3;
            }
            zz[bb] = z;
            ss[bb][0] = s0; ss[bb][1] = s1; ss[bb][2] = s2; ss[bb][3] = s3;
        }
        #pragma unroll
        for (int off = 4; off <= 32; off <<= 1) {
            #pragma unroll
            for (int bb = 0; bb < BPB; ++bb) {
                zz[bb] += __shfl_xor(zz[bb], off);
                ss[bb][0] += __shfl_xor(ss[bb][0], off);
                ss[bb][1] += __shfl_xor(ss[bb][1], off);
                ss[bb][2] += __shfl_xor(ss[bb][2], off);
                ss[bb][3] += __shfl_xor(ss[bb][3], off);
            }
        }
        if (lane < 4) {
            #pragma unroll
            for (int bb = 0; bb < BPB; ++bb) {
                sred[bb][wid][lane][0] = ss[bb][0];
                sred[bb][wid][lane][1] = ss[bb][1];
                sred[bb][wid][lane][2] = ss[bb][2];
                sred[bb][wid][lane][3] = ss[bb][3];
                if (lane == 0) zred[bb][wid] = zz[bb];
            }
        }
        __syncthreads();

        if (wid == 0) {
            const int bb = lane >> 4;
            const int o  = lane & 15;
            float S = 0.f, Z = 0.f;
            #pragma unroll
            for (int wv = 0; wv < NW; ++wv) {
                S += sred[bb][wv][o >> 2][o & 3];
                Z += zred[bb][wv];
            }
            const float inv = 1.f / Z;
            const float svn = S * inv;
            float p = svn * svn;
            p += __shfl_xor(p, 1);
            p += __shfl_xor(p, 2);
            p += __shfl_xor(p, 4);
            p += __shfl_xor(p, 8);
            const float scale = sqrtf(p) / (1.f + p);
            const float vf = svn * scale;
            vsum[bb][o] += vf;
            if (it == NITER - 1)
                out[((size_t)(b0 + bb) * C_ + c) * O_ + o] = vf;
        }
        if (it != NITER - 1) __syncthreads();
    }
}

extern "C" void kernel_launch(void* const* d_in, const int* in_sizes, int n_in,
                              void* d_out, int out_size, void* d_ws, size_t ws_size,
                              hipStream_t stream) {
    const float* x = (const float*)d_in[0];
    const float* w = (const float*)d_in[1];
    float* out = (float*)d_out;

    const size_t u_bytes = (size_t)B_ * C_ * KPT * T_ * 8;   // 94,371,840
    if (ws_size >= u_bytes) {
        uint2* u = (uint2*)d_ws;
        caps_u_kernel<<<dim3(C_ * KPT * 32), dim3(T_), 0, stream>>>(x, w, u);
        caps_route_kernel<<<dim3(B_ * C_), dim3(T_), 0, stream>>>(u, out);
    } else {
        capsule_fused_kernel<<<dim3(C_ * (B_ / BPB)), dim3(T_), 0, stream>>>(x, w, out);
    }
}